// Round 10
// baseline (260.074 us; speedup 1.0000x reference)
//
#include <hip/hip_runtime.h>
#include <math.h>

#define Dm   768
#define Hm   64
#define SEQ  4096
#define NB   4
#define NROW (NB * SEQ)

// scale 1/sqrt(64) and log2(e) folded into Wq at wconv time -> exp2 domain
#define QSCALE (0.125f * 1.4426950408889634f)

typedef _Float16 f16;
typedef __attribute__((ext_vector_type(8))) _Float16 f16x8;
typedef __attribute__((ext_vector_type(2))) __fp16 fp16x2_raw;
typedef __attribute__((ext_vector_type(4))) float f32x4;
typedef unsigned int uint;
typedef unsigned short ushort;

#define MFMAH(A, B, C) __builtin_amdgcn_mfma_f32_16x16x32_f16(A, B, C, 0, 0, 0)

__device__ __forceinline__ uint pkrtz(float a, float b) {
    fp16x2_raw r = __builtin_amdgcn_cvt_pkrtz(a, b);
    return __builtin_bit_cast(uint, r);
}
__device__ __forceinline__ ushort f2h(float f) {
    f16 h = (f16)f;
    return __builtin_bit_cast(ushort, h);
}
union F16x8U { uint u[4]; f16x8 v; };

// ---------------------------------------------------------------------------
// Kernel 0: W -> WTt f16, tiled [kt(24)][c(192)][kk(32)]. Coalesced via
// padded-LDS transpose. (Measured good — unchanged.)
// ---------------------------------------------------------------------------
__global__ __launch_bounds__(256) void wconv(
    const float* __restrict__ Wq, const float* __restrict__ Wk,
    const float* __restrict__ Wv, ushort* __restrict__ WTt)
{
    __shared__ ushort lt[64 * 33];
    const int b  = blockIdx.x;            // 72 = 24 kt x 3 mat
    const int kt = b / 3, m = b - kt * 3;
    const float* W = (m == 0) ? Wq : (m == 1 ? Wk : Wv);
    const float sc = (m == 0) ? QSCALE : 1.0f;
    const int t = threadIdx.x;
#pragma unroll
    for (int p = 0; p < 8; ++p) {
        int t2 = p * 256 + t;
        int kl = t2 >> 6, c = t2 & 63;
        lt[c * 33 + kl] = f2h(W[(size_t)(kt * 32 + kl) * 64 + c] * sc);
    }
    __syncthreads();
#pragma unroll
    for (int p = 0; p < 8; ++p) {
        int t2 = p * 256 + t;
        int c = t2 >> 5, kk = t2 & 31;
        WTt[((size_t)kt * 192 + m * 64 + c) * 32 + kk] = lt[c * 33 + kk];
    }
}

// ---------------------------------------------------------------------------
// Kernel 1: f16 MFMA QKV projection, split-K=4, 32 rows/block (512 blocks).
// B-fragment set reused across two 16-row tiles. LB(256,2) [= 2 blocks/CU,
// VGPR cap 256 per the R8/R9-calibrated rule cap=512/(arg*B/256)].
// (R4/R5 measured-good body — unchanged.)
// ---------------------------------------------------------------------------
__global__ __launch_bounds__(256, 2) void proj(
    const float* __restrict__ ix, const ushort* __restrict__ WTt,
    ushort* __restrict__ Qw, ushort* __restrict__ Kt, ushort* __restrict__ Vt)
{
    __shared__ __align__(16) float comb[2][2][3072];   // 48 KiB

    const int t    = threadIdx.x;
    const int lane = t & 63;
    const int kh   = __builtin_amdgcn_readfirstlane(t >> 6);  // split-K index
    const int q15  = lane & 15, quad = lane >> 4;
    const int gr0  = blockIdx.x * 32;

    const float* Ab0 = ix + (size_t)(gr0 + q15) * Dm + kh * 192 + quad * 8;
    const float* Ab1 = Ab0 + (size_t)16 * Dm;
    const ushort* Bb = WTt + ((size_t)(kh * 6) * 192 + q15) * 32 + quad * 8;

    f32x4 acc[2][12];
#pragma unroll
    for (int rt = 0; rt < 2; ++rt)
#pragma unroll
        for (int ct = 0; ct < 12; ++ct) acc[rt][ct] = (f32x4){0.f, 0.f, 0.f, 0.f};

    f32x4 Af[2][3][2];   // [tile][ring-3][half], distance-2
#pragma unroll
    for (int i = 0; i < 2; ++i) {
        Af[0][i][0] = *(const f32x4*)(Ab0 + i * 32);
        Af[0][i][1] = *(const f32x4*)(Ab0 + i * 32 + 4);
        Af[1][i][0] = *(const f32x4*)(Ab1 + i * 32);
        Af[1][i][1] = *(const f32x4*)(Ab1 + i * 32 + 4);
    }

#pragma unroll
    for (int it = 0; it < 6; ++it) {
        f16x8 Bf[12];
#pragma unroll
        for (int ct = 0; ct < 12; ++ct)
            Bf[ct] = *(const f16x8*)(Bb + (size_t)it * 6144 + ct * 512);

        if (it + 2 < 6) {
            Af[0][(it + 2) % 3][0] = *(const f32x4*)(Ab0 + (it + 2) * 32);
            Af[0][(it + 2) % 3][1] = *(const f32x4*)(Ab0 + (it + 2) * 32 + 4);
            Af[1][(it + 2) % 3][0] = *(const f32x4*)(Ab1 + (it + 2) * 32);
            Af[1][(it + 2) % 3][1] = *(const f32x4*)(Ab1 + (it + 2) * 32 + 4);
        }

        F16x8U af0, af1;
        af0.u[0] = pkrtz(Af[0][it % 3][0].x, Af[0][it % 3][0].y);
        af0.u[1] = pkrtz(Af[0][it % 3][0].z, Af[0][it % 3][0].w);
        af0.u[2] = pkrtz(Af[0][it % 3][1].x, Af[0][it % 3][1].y);
        af0.u[3] = pkrtz(Af[0][it % 3][1].z, Af[0][it % 3][1].w);
        af1.u[0] = pkrtz(Af[1][it % 3][0].x, Af[1][it % 3][0].y);
        af1.u[1] = pkrtz(Af[1][it % 3][0].z, Af[1][it % 3][0].w);
        af1.u[2] = pkrtz(Af[1][it % 3][1].x, Af[1][it % 3][1].y);
        af1.u[3] = pkrtz(Af[1][it % 3][1].z, Af[1][it % 3][1].w);
        __builtin_amdgcn_s_setprio(1);
#pragma unroll
        for (int ct = 0; ct < 12; ++ct) {
            acc[0][ct] = MFMAH(af0.v, Bf[ct], acc[0][ct]);
            acc[1][ct] = MFMAH(af1.v, Bf[ct], acc[1][ct]);
        }
        __builtin_amdgcn_s_setprio(0);
    }

    if (kh >= 2) {
#pragma unroll
        for (int rt = 0; rt < 2; ++rt)
#pragma unroll
            for (int ct = 0; ct < 12; ++ct)
                *(f32x4*)&comb[rt][kh - 2][(ct * 64 + lane) * 4] = acc[rt][ct];
    }
    __syncthreads();
    if (kh < 2) {
#pragma unroll
        for (int rt = 0; rt < 2; ++rt)
#pragma unroll
            for (int ct = 0; ct < 12; ++ct) {
                f32x4 o = *(const f32x4*)&comb[rt][kh][(ct * 64 + lane) * 4];
                acc[rt][ct].x += o.x; acc[rt][ct].y += o.y;
                acc[rt][ct].z += o.z; acc[rt][ct].w += o.w;
            }
    }
    __syncthreads();
    if (kh == 1) {
#pragma unroll
        for (int rt = 0; rt < 2; ++rt)
#pragma unroll
            for (int ct = 0; ct < 12; ++ct)
                *(f32x4*)&comb[rt][0][(ct * 64 + lane) * 4] = acc[rt][ct];
    }
    __syncthreads();
    if (kh == 0) {
#pragma unroll
        for (int rt = 0; rt < 2; ++rt) {
#pragma unroll
            for (int ct = 0; ct < 12; ++ct) {
                f32x4 o = *(const f32x4*)&comb[rt][0][(ct * 64 + lane) * 4];
                acc[rt][ct].x += o.x; acc[rt][ct].y += o.y;
                acc[rt][ct].z += o.z; acc[rt][ct].w += o.w;
            }
            const int gr  = gr0 + rt * 16;
            const int n4  = gr >> 4;
            const int h16 = n4 & 1;
            const int j32 = gr >> 5;
#pragma unroll
            for (int ct = 0; ct < 12; ++ct) {
                float vals[4] = {acc[rt][ct].x, acc[rt][ct].y, acc[rt][ct].z, acc[rt][ct].w};
                if (ct < 4) {
#pragma unroll
                    for (int r = 0; r < 4; ++r)
                        Qw[(size_t)(gr + quad * 4 + r) * 64 + ct * 16 + q15] = f2h(vals[r]);
                } else if (ct < 8) {
#pragma unroll
                    for (int r = 0; r < 4; ++r)
                        Kt[(size_t)n4 * 1024 + (ct - 4) * 256 + (quad * 4 + r) * 16 + q15] = f2h(vals[r]);
                } else {
                    ushort4 vv;
                    vv.x = f2h(vals[0]); vv.y = f2h(vals[1]);
                    vv.z = f2h(vals[2]); vv.w = f2h(vals[3]);
                    *(ushort4*)(Vt + (size_t)j32 * 2048 + (ct - 8) * 512 +
                                (h16 * 2 + (quad >> 1)) * 128 + q15 * 8 + (quad & 1) * 4) = vv;
                }
            }
        }
    }
}

// ---------------------------------------------------------------------------
// Kernel 2: f16 MFMA flash attention, 16-WAVE BLOCKS. grid 256 x 1024.
// Monolithic (R9's j-split reverted: 26->43us regression, occupancy flat at
// ~18%). Same measured body (VGPR 112); occupancy doubled INSIDE the block:
// 16 waves x j-range 256 (8 iters of 32 keys) -> 4 waves/SIMD on 1 block/CU.
// LB(1024,1): calibrated rule cap = 512/(arg*B/256) = 128 >= 112, no spill.
// LDS: P strips 16 x 2buf x 64q x 34 shorts = 136KB (+4KB l) = 140KB/CU.
// PSTR=34 words17: gcd(17,32)=1 -> conflict-free rows. No partials/fincomb.
// ---------------------------------------------------------------------------
#define PSTR 34          // P strip row stride (shorts): 32 j + 2 pad
#define PBUF 2176        // one buf: 64 q x 34 shorts
#define PWAVE 4352       // 2 bufs per wave (shorts)
#define OSTR 68
#define OBUF 4352        // 64 rows x 68 floats per combine buffer
#define LOFF 34816       // floats: l region after 139264B of P strips

__global__ __launch_bounds__(1024, 1) void attn(
    const ushort* __restrict__ Qw, const ushort* __restrict__ Kt,
    const ushort* __restrict__ Vt, float* __restrict__ out)
{
    // shorts [0, 69632): P strips (16 waves x 4352). After the loop the float
    // view is reused: 8 combine bufs x 4352 floats = exactly [0, 34816).
    // floats [34816, 35840): l per wave. Total 143360 B, 1 block/CU.
    __shared__ __align__(16) float aF[35840];
    short* aS = (short*)aF;

    const int t    = threadIdx.x;
    const int lane = t & 63;
    const int w    = __builtin_amdgcn_readfirstlane(t >> 6);   // 0..15
    const int q15  = lane & 15, quad = lane >> 4;

    const int bb    = blockIdx.x;
    const int xcd   = bb & 7;
    const int batch = xcd >> 1;
    const int slot  = (bb >> 3) | ((xcd & 1) << 5);   // 0..63
    const int q0    = slot * 64;
    const size_t base = (size_t)batch * SEQ;

    f16x8 qf[4][2];
#pragma unroll
    for (int g = 0; g < 4; ++g)
#pragma unroll
        for (int h = 0; h < 2; ++h)
            qf[g][h] = *(const f16x8*)(Qw + (base + q0 + g * 16 + q15) * 64 + h * 32 + quad * 8);

    f32x4 oacc[4][4];
#pragma unroll
    for (int g = 0; g < 4; ++g)
#pragma unroll
        for (int dt = 0; dt < 4; ++dt) oacc[g][dt] = (f32x4){0.f, 0.f, 0.f, 0.f};
    float lsum[4] = {0.f, 0.f, 0.f, 0.f};

    const size_t j0g = base + w * 256;                 // 16 waves x 256 j
    const ushort* Kfb = Kt + (j0g >> 4) * 1024;
    const ushort* Vfb = Vt + (j0g >> 5) * 2048 + lane * 8;
    short* Ps = aS + w * PWAVE;

    int koff[2][2];
#pragma unroll
    for (int jt = 0; jt < 2; ++jt)
#pragma unroll
        for (int h = 0; h < 2; ++h)
            koff[jt][h] = jt * 1024 + h * 512 + (quad >> 1) * 256 + q15 * 16 + (quad & 1) * 8;

    f16x8 kf[2][2][2], vf[2][4];   // ring-2
    f32x4 zz[4][2];                // deferred QK results (tile i+1)
    f16x8 pf[4];

#define LOADKV(slotc, i)                                                       \
    {                                                                          \
        _Pragma("unroll") for (int jt = 0; jt < 2; ++jt)                       \
        _Pragma("unroll") for (int h = 0; h < 2; ++h)                          \
            kf[slotc][jt][h] = *(const f16x8*)(Kfb + (size_t)(i) * 2048 + koff[jt][h]); \
        _Pragma("unroll") for (int dt = 0; dt < 4; ++dt)                       \
            vf[slotc][dt] = *(const f16x8*)(Vfb + (size_t)(i) * 2048 + dt * 512); \
    }
#define QKMM(slotc)                                                            \
    {                                                                          \
        _Pragma("unroll") for (int g = 0; g < 4; ++g)                          \
        _Pragma("unroll") for (int jt = 0; jt < 2; ++jt) {                     \
            f32x4 z = (f32x4){0.f, 0.f, 0.f, 0.f};                             \
            z = MFMAH(kf[slotc][jt][0], qf[g][0], z);                          \
            z = MFMAH(kf[slotc][jt][1], qf[g][1], z);                          \
            zz[g][jt] = z;                                                     \
        }                                                                      \
    }
#define SMPACK(pb)                                                             \
    {                                                                          \
        _Pragma("unroll") for (int g = 0; g < 4; ++g)                          \
        _Pragma("unroll") for (int jt = 0; jt < 2; ++jt) {                     \
            float e0 = exp2f(zz[g][jt].x), e1 = exp2f(zz[g][jt].y);            \
            float e2 = exp2f(zz[g][jt].z), e3 = exp2f(zz[g][jt].w);            \
            lsum[g] += (e0 + e1) + (e2 + e3);                                  \
            uint2 pk = make_uint2(pkrtz(e0, e1), pkrtz(e2, e3));               \
            *(uint2*)(Ps + (pb) * PBUF + (g * 16 + q15) * PSTR + jt * 16 + quad * 4) = pk; \
        }                                                                      \
    }
#define PFLOAD(pb)                                                             \
    {                                                                          \
        _Pragma("unroll") for (int g = 0; g < 4; ++g)                          \
            pf[g] = *(const f16x8*)(Ps + (pb) * PBUF + (g * 16 + q15) * PSTR + quad * 8); \
    }
#define PVMM(slotc)                                                            \
    {                                                                          \
        _Pragma("unroll") for (int dt = 0; dt < 4; ++dt)                       \
        _Pragma("unroll") for (int g = 0; g < 4; ++g)                          \
            oacc[g][dt] = MFMAH(pf[g], vf[slotc][dt], oacc[g][dt]);            \
    }

    LOADKV(0, 0);
    LOADKV(1, 1);
    QKMM(0);
    SMPACK(0);
#pragma unroll
    for (int i = 0; i < 8; ++i) {
        PFLOAD(i & 1);
        __builtin_amdgcn_s_setprio(1);
        if (i + 1 < 8) QKMM((i + 1) & 1);
        PVMM(i & 1);
        __builtin_amdgcn_s_setprio(0);
        if (i + 2 < 8) LOADKV(i & 1, i + 2);
        if (i + 1 < 8) SMPACK((i + 1) & 1);
    }

    // ---- l: quad-reduce, publish per wave ----
#pragma unroll
    for (int g = 0; g < 4; ++g) {
        lsum[g] += __shfl_xor(lsum[g], 16);
        lsum[g] += __shfl_xor(lsum[g], 32);
    }
    if (quad == 0) {
#pragma unroll
        for (int g = 0; g < 4; ++g)
            aF[LOFF + w * 64 + g * 16 + q15] = lsum[g];
    }
    __syncthreads();   // P strips dead; l published; combine bufs usable

    // ---- 16-way tree combine of o through LDS (8 bufs, rows OSTR=68) ----
#define OWRITE(idx)                                                          \
    {                                                                        \
        float* b = aF + (idx) * OBUF;                                        \
        _Pragma("unroll") for (int g = 0; g < 4; ++g)                        \
        _Pragma("unroll") for (int dt = 0; dt < 4; ++dt) {                   \
            b[(g * 16 + quad * 4 + 0) * OSTR + dt * 16 + q15] = oacc[g][dt].x; \
            b[(g * 16 + quad * 4 + 1) * OSTR + dt * 16 + q15] = oacc[g][dt].y; \
            b[(g * 16 + quad * 4 + 2) * OSTR + dt * 16 + q15] = oacc[g][dt].z; \
            b[(g * 16 + quad * 4 + 3) * OSTR + dt * 16 + q15] = oacc[g][dt].w; \
        }                                                                    \
    }
#define OADD(idx)                                                            \
    {                                                                        \
        const float* b = aF + (idx) * OBUF;                                  \
        _Pragma("unroll") for (int g = 0; g < 4; ++g)                        \
        _Pragma("unroll") for (int dt = 0; dt < 4; ++dt) {                   \
            oacc[g][dt].x += b[(g * 16 + quad * 4 + 0) * OSTR + dt * 16 + q15];\
            oacc[g][dt].y += b[(g * 16 + quad * 4 + 1) * OSTR + dt * 16 + q15];\
            oacc[g][dt].z += b[(g * 16 + quad * 4 + 2) * OSTR + dt * 16 + q15];\
            oacc[g][dt].w += b[(g * 16 + quad * 4 + 3) * OSTR + dt * 16 + q15];\
        }                                                                    \
    }
    if (w >= 8) OWRITE(w - 8);
    __syncthreads();
    if (w < 8) OADD(w);
    __syncthreads();
    if (w >= 4 && w < 8) OWRITE(w - 4);
    __syncthreads();
    if (w < 4) OADD(w);
    __syncthreads();
    if (w == 2 || w == 3) OWRITE(w - 2);
    __syncthreads();
    if (w < 2) OADD(w);
    __syncthreads();
    if (w < 2) OWRITE(w);
    __syncthreads();

    {
        const int q  = t >> 4;            // 0..63
        const int d0 = (t & 15) * 4;      // one float4 per thread
        float l = 0.f;
#pragma unroll
        for (int i = 0; i < 16; ++i) l += aF[LOFF + i * 64 + q];
        const float linv = 1.0f / l;
        float4 a = *(const float4*)&aF[q * OSTR + d0];
        float4 b = *(const float4*)&aF[OBUF + q * OSTR + d0];
        float4 s;
        s.x = (a.x + b.x) * linv; s.y = (a.y + b.y) * linv;
        s.z = (a.z + b.z) * linv; s.w = (a.w + b.w) * linv;
        *(float4*)(out + (base + q0 + q) * 64 + d0) = s;
    }
}

// ---------------------------------------------------------------------------
extern "C" void kernel_launch(void* const* d_in, const int* in_sizes, int n_in,
                              void* d_out, int out_size, void* d_ws, size_t ws_size,
                              hipStream_t stream)
{
    const float* ix = (const float*)d_in[0];
    const float* Wk = (const float*)d_in[1];
    const float* Wq = (const float*)d_in[2];
    const float* Wv = (const float*)d_in[3];
    float* out = (float*)d_out;

    // ws: Qw | Kt | Vt (NROW*64 ushorts each) + WTt (24*192*32 ushorts)
    ushort* Qw  = (ushort*)d_ws;
    ushort* Kt  = Qw + (size_t)NROW * Hm;
    ushort* Vt  = Kt + (size_t)NROW * Hm;
    ushort* WTt = Vt + (size_t)NROW * Hm;

    wconv<<<72, 256, 0, stream>>>(Wq, Wk, Wv, WTt);
    proj<<<512, 256, 0, stream>>>(ix, WTt, Qw, Kt, Vt);
    attn<<<256, 1024, 0, stream>>>(Qw, Kt, Vt, out);
}

// Round 11
// 129.443 us; speedup vs baseline: 2.0092x; 2.0092x over previous
//
#include <hip/hip_runtime.h>
#include <math.h>

#define Dm   768
#define Hm   64
#define SEQ  4096
#define NB   4
#define NROW (NB * SEQ)

// scale 1/sqrt(64) and log2(e) folded into Wq at wconv time -> exp2 domain
#define QSCALE (0.125f * 1.4426950408889634f)

typedef _Float16 f16;
typedef __attribute__((ext_vector_type(8))) _Float16 f16x8;
typedef __attribute__((ext_vector_type(2))) __fp16 fp16x2_raw;
typedef __attribute__((ext_vector_type(4))) float f32x4;
typedef unsigned int uint;
typedef unsigned short ushort;

#define MFMAH(A, B, C) __builtin_amdgcn_mfma_f32_16x16x32_f16(A, B, C, 0, 0, 0)

__device__ __forceinline__ uint pkrtz(float a, float b) {
    fp16x2_raw r = __builtin_amdgcn_cvt_pkrtz(a, b);
    return __builtin_bit_cast(uint, r);
}
__device__ __forceinline__ ushort f2h(float f) {
    f16 h = (f16)f;
    return __builtin_bit_cast(ushort, h);
}
union F16x8U { uint u[4]; f16x8 v; };

// ---------------------------------------------------------------------------
// Kernel 0: W -> WTt f16, tiled [kt(24)][c(192)][kk(32)]. Coalesced via
// padded-LDS transpose. (Measured good — unchanged.)
// ---------------------------------------------------------------------------
__global__ __launch_bounds__(256) void wconv(
    const float* __restrict__ Wq, const float* __restrict__ Wk,
    const float* __restrict__ Wv, ushort* __restrict__ WTt)
{
    __shared__ ushort lt[64 * 33];
    const int b  = blockIdx.x;            // 72 = 24 kt x 3 mat
    const int kt = b / 3, m = b - kt * 3;
    const float* W = (m == 0) ? Wq : (m == 1 ? Wk : Wv);
    const float sc = (m == 0) ? QSCALE : 1.0f;
    const int t = threadIdx.x;
#pragma unroll
    for (int p = 0; p < 8; ++p) {
        int t2 = p * 256 + t;
        int kl = t2 >> 6, c = t2 & 63;
        lt[c * 33 + kl] = f2h(W[(size_t)(kt * 32 + kl) * 64 + c] * sc);
    }
    __syncthreads();
#pragma unroll
    for (int p = 0; p < 8; ++p) {
        int t2 = p * 256 + t;
        int c = t2 >> 5, kk = t2 & 31;
        WTt[((size_t)kt * 192 + m * 64 + c) * 32 + kk] = lt[c * 33 + kk];
    }
}

// ---------------------------------------------------------------------------
// Kernel 1: f16 MFMA QKV projection, split-K=4, 32 rows/block (512 blocks).
// B-fragment set reused across two 16-row tiles. LB(256,2), 2 blocks/CU.
// (R4/R5 measured-good body — unchanged.)
// ---------------------------------------------------------------------------
__global__ __launch_bounds__(256, 2) void proj(
    const float* __restrict__ ix, const ushort* __restrict__ WTt,
    ushort* __restrict__ Qw, ushort* __restrict__ Kt, ushort* __restrict__ Vt)
{
    __shared__ __align__(16) float comb[2][2][3072];   // 48 KiB

    const int t    = threadIdx.x;
    const int lane = t & 63;
    const int kh   = __builtin_amdgcn_readfirstlane(t >> 6);  // split-K index
    const int q15  = lane & 15, quad = lane >> 4;
    const int gr0  = blockIdx.x * 32;

    const float* Ab0 = ix + (size_t)(gr0 + q15) * Dm + kh * 192 + quad * 8;
    const float* Ab1 = Ab0 + (size_t)16 * Dm;
    const ushort* Bb = WTt + ((size_t)(kh * 6) * 192 + q15) * 32 + quad * 8;

    f32x4 acc[2][12];
#pragma unroll
    for (int rt = 0; rt < 2; ++rt)
#pragma unroll
        for (int ct = 0; ct < 12; ++ct) acc[rt][ct] = (f32x4){0.f, 0.f, 0.f, 0.f};

    f32x4 Af[2][3][2];   // [tile][ring-3][half], distance-2
#pragma unroll
    for (int i = 0; i < 2; ++i) {
        Af[0][i][0] = *(const f32x4*)(Ab0 + i * 32);
        Af[0][i][1] = *(const f32x4*)(Ab0 + i * 32 + 4);
        Af[1][i][0] = *(const f32x4*)(Ab1 + i * 32);
        Af[1][i][1] = *(const f32x4*)(Ab1 + i * 32 + 4);
    }

#pragma unroll
    for (int it = 0; it < 6; ++it) {
        f16x8 Bf[12];
#pragma unroll
        for (int ct = 0; ct < 12; ++ct)
            Bf[ct] = *(const f16x8*)(Bb + (size_t)it * 6144 + ct * 512);

        if (it + 2 < 6) {
            Af[0][(it + 2) % 3][0] = *(const f32x4*)(Ab0 + (it + 2) * 32);
            Af[0][(it + 2) % 3][1] = *(const f32x4*)(Ab0 + (it + 2) * 32 + 4);
            Af[1][(it + 2) % 3][0] = *(const f32x4*)(Ab1 + (it + 2) * 32);
            Af[1][(it + 2) % 3][1] = *(const f32x4*)(Ab1 + (it + 2) * 32 + 4);
        }

        F16x8U af0, af1;
        af0.u[0] = pkrtz(Af[0][it % 3][0].x, Af[0][it % 3][0].y);
        af0.u[1] = pkrtz(Af[0][it % 3][0].z, Af[0][it % 3][0].w);
        af0.u[2] = pkrtz(Af[0][it % 3][1].x, Af[0][it % 3][1].y);
        af0.u[3] = pkrtz(Af[0][it % 3][1].z, Af[0][it % 3][1].w);
        af1.u[0] = pkrtz(Af[1][it % 3][0].x, Af[1][it % 3][0].y);
        af1.u[1] = pkrtz(Af[1][it % 3][0].z, Af[1][it % 3][0].w);
        af1.u[2] = pkrtz(Af[1][it % 3][1].x, Af[1][it % 3][1].y);
        af1.u[3] = pkrtz(Af[1][it % 3][1].z, Af[1][it % 3][1].w);
        __builtin_amdgcn_s_setprio(1);
#pragma unroll
        for (int ct = 0; ct < 12; ++ct) {
            acc[0][ct] = MFMAH(af0.v, Bf[ct], acc[0][ct]);
            acc[1][ct] = MFMAH(af1.v, Bf[ct], acc[1][ct]);
        }
        __builtin_amdgcn_s_setprio(0);
    }

    if (kh >= 2) {
#pragma unroll
        for (int rt = 0; rt < 2; ++rt)
#pragma unroll
            for (int ct = 0; ct < 12; ++ct)
                *(f32x4*)&comb[rt][kh - 2][(ct * 64 + lane) * 4] = acc[rt][ct];
    }
    __syncthreads();
    if (kh < 2) {
#pragma unroll
        for (int rt = 0; rt < 2; ++rt)
#pragma unroll
            for (int ct = 0; ct < 12; ++ct) {
                f32x4 o = *(const f32x4*)&comb[rt][kh][(ct * 64 + lane) * 4];
                acc[rt][ct].x += o.x; acc[rt][ct].y += o.y;
                acc[rt][ct].z += o.z; acc[rt][ct].w += o.w;
            }
    }
    __syncthreads();
    if (kh == 1) {
#pragma unroll
        for (int rt = 0; rt < 2; ++rt)
#pragma unroll
            for (int ct = 0; ct < 12; ++ct)
                *(f32x4*)&comb[rt][0][(ct * 64 + lane) * 4] = acc[rt][ct];
    }
    __syncthreads();
    if (kh == 0) {
#pragma unroll
        for (int rt = 0; rt < 2; ++rt) {
#pragma unroll
            for (int ct = 0; ct < 12; ++ct) {
                f32x4 o = *(const f32x4*)&comb[rt][0][(ct * 64 + lane) * 4];
                acc[rt][ct].x += o.x; acc[rt][ct].y += o.y;
                acc[rt][ct].z += o.z; acc[rt][ct].w += o.w;
            }
            const int gr  = gr0 + rt * 16;
            const int n4  = gr >> 4;
            const int h16 = n4 & 1;
            const int j32 = gr >> 5;
#pragma unroll
            for (int ct = 0; ct < 12; ++ct) {
                float vals[4] = {acc[rt][ct].x, acc[rt][ct].y, acc[rt][ct].z, acc[rt][ct].w};
                if (ct < 4) {
#pragma unroll
                    for (int r = 0; r < 4; ++r)
                        Qw[(size_t)(gr + quad * 4 + r) * 64 + ct * 16 + q15] = f2h(vals[r]);
                } else if (ct < 8) {
#pragma unroll
                    for (int r = 0; r < 4; ++r)
                        Kt[(size_t)n4 * 1024 + (ct - 4) * 256 + (quad * 4 + r) * 16 + q15] = f2h(vals[r]);
                } else {
                    ushort4 vv;
                    vv.x = f2h(vals[0]); vv.y = f2h(vals[1]);
                    vv.z = f2h(vals[2]); vv.w = f2h(vals[3]);
                    *(ushort4*)(Vt + (size_t)j32 * 2048 + (ct - 8) * 512 +
                                (h16 * 2 + (quad >> 1)) * 128 + q15 * 8 + (quad & 1) * 4) = vv;
                }
            }
        }
    }
}

// ---------------------------------------------------------------------------
// Kernel 2: f16 MFMA flash attention — R5 monolithic structure (measured
// best: 16 iters/wave, 512 thr, LB(512,2) => 112-128 VGPR, no spill), with
// LDS squeezed 84 -> 72 KB EXACTLY so two blocks can co-reside per CU
// (2 x 73728 = 147456 <= 163840 with 16KB slack; R9's 75776B version never
// co-scheduled — granularity suspect). Changes vs R5: PSTR 40->36 shorts
// (row 72B: bank = 18*row mod 32, gcd(18,32)=2 -> 16 distinct banks, clean),
// l-region relocated INSIDE the P footprint and published after the first
// barrier (P strips dead there). Body/pipeline/numerics identical to R5.
// ---------------------------------------------------------------------------
#define PSTR 36          // P strip row stride (shorts): 32 j + 4 pad
#define PBUF 2304        // one buf: 64 q x 36 shorts
#define PWAVE 4608       // 2 bufs per wave (shorts)
#define OSTR 68
#define OBUF 4352        // 64 rows x 68 floats per combine buffer
#define LOFF 17408       // floats: l region right after 4 combine bufs

__global__ __launch_bounds__(512, 2) void attn(
    const ushort* __restrict__ Qw, const ushort* __restrict__ Kt,
    const ushort* __restrict__ Vt, float* __restrict__ out)
{
    // shorts [0, 36864): P strips (8 waves x 4608) = 73728 B total LDS.
    // After loop + barrier (P dead), float view: [0,17408) = 4 combine bufs,
    // [17408, 17920) = l per wave — both inside the 73728B footprint.
    __shared__ __align__(16) float aF[18432];   // 73728 B
    short* aS = (short*)aF;

    const int t    = threadIdx.x;
    const int lane = t & 63;
    const int w    = __builtin_amdgcn_readfirstlane(t >> 6);
    const int q15  = lane & 15, quad = lane >> 4;

    const int bb    = blockIdx.x;
    const int xcd   = bb & 7;
    const int batch = xcd >> 1;
    const int slot  = (bb >> 3) | ((xcd & 1) << 5);   // 0..63
    const int q0    = slot * 64;
    const size_t base = (size_t)batch * SEQ;

    f16x8 qf[4][2];
#pragma unroll
    for (int g = 0; g < 4; ++g)
#pragma unroll
        for (int h = 0; h < 2; ++h)
            qf[g][h] = *(const f16x8*)(Qw + (base + q0 + g * 16 + q15) * 64 + h * 32 + quad * 8);

    f32x4 oacc[4][4];
#pragma unroll
    for (int g = 0; g < 4; ++g)
#pragma unroll
        for (int dt = 0; dt < 4; ++dt) oacc[g][dt] = (f32x4){0.f, 0.f, 0.f, 0.f};
    float lsum[4] = {0.f, 0.f, 0.f, 0.f};

    const size_t j0g = base + w * 512;
    const ushort* Kfb = Kt + (j0g >> 4) * 1024;
    const ushort* Vfb = Vt + (j0g >> 5) * 2048 + lane * 8;
    short* Ps = aS + w * PWAVE;

    int koff[2][2];
#pragma unroll
    for (int jt = 0; jt < 2; ++jt)
#pragma unroll
        for (int h = 0; h < 2; ++h)
            koff[jt][h] = jt * 1024 + h * 512 + (quad >> 1) * 256 + q15 * 16 + (quad & 1) * 8;

    f16x8 kf[2][2][2], vf[2][4];   // ring-2
    f32x4 zz[4][2];                // deferred QK results (tile i+1)
    f16x8 pf[4];

#define LOADKV(slotc, i)                                                       \
    {                                                                          \
        _Pragma("unroll") for (int jt = 0; jt < 2; ++jt)                       \
        _Pragma("unroll") for (int h = 0; h < 2; ++h)                          \
            kf[slotc][jt][h] = *(const f16x8*)(Kfb + (size_t)(i) * 2048 + koff[jt][h]); \
        _Pragma("unroll") for (int dt = 0; dt < 4; ++dt)                       \
            vf[slotc][dt] = *(const f16x8*)(Vfb + (size_t)(i) * 2048 + dt * 512); \
    }
#define QKMM(slotc)                                                            \
    {                                                                          \
        _Pragma("unroll") for (int g = 0; g < 4; ++g)                          \
        _Pragma("unroll") for (int jt = 0; jt < 2; ++jt) {                     \
            f32x4 z = (f32x4){0.f, 0.f, 0.f, 0.f};                             \
            z = MFMAH(kf[slotc][jt][0], qf[g][0], z);                          \
            z = MFMAH(kf[slotc][jt][1], qf[g][1], z);                          \
            zz[g][jt] = z;                                                     \
        }                                                                      \
    }
#define SMPACK(pb)                                                             \
    {                                                                          \
        _Pragma("unroll") for (int g = 0; g < 4; ++g)                          \
        _Pragma("unroll") for (int jt = 0; jt < 2; ++jt) {                     \
            float e0 = exp2f(zz[g][jt].x), e1 = exp2f(zz[g][jt].y);            \
            float e2 = exp2f(zz[g][jt].z), e3 = exp2f(zz[g][jt].w);            \
            lsum[g] += (e0 + e1) + (e2 + e3);                                  \
            uint2 pk = make_uint2(pkrtz(e0, e1), pkrtz(e2, e3));               \
            *(uint2*)(Ps + (pb) * PBUF + (g * 16 + q15) * PSTR + jt * 16 + quad * 4) = pk; \
        }                                                                      \
    }
#define PFLOAD(pb)                                                             \
    {                                                                          \
        _Pragma("unroll") for (int g = 0; g < 4; ++g)                          \
            pf[g] = *(const f16x8*)(Ps + (pb) * PBUF + (g * 16 + q15) * PSTR + quad * 8); \
    }
#define PVMM(slotc)                                                            \
    {                                                                          \
        _Pragma("unroll") for (int dt = 0; dt < 4; ++dt)                       \
        _Pragma("unroll") for (int g = 0; g < 4; ++g)                          \
            oacc[g][dt] = MFMAH(pf[g], vf[slotc][dt], oacc[g][dt]);            \
    }

    LOADKV(0, 0);
    LOADKV(1, 1);
    QKMM(0);
    SMPACK(0);
#pragma unroll
    for (int i = 0; i < 16; ++i) {
        PFLOAD(i & 1);
        __builtin_amdgcn_s_setprio(1);
        if (i + 1 < 16) QKMM((i + 1) & 1);
        PVMM(i & 1);
        __builtin_amdgcn_s_setprio(0);
        if (i + 2 < 16) LOADKV(i & 1, i + 2);
        if (i + 1 < 16) SMPACK((i + 1) & 1);
    }

    // ---- l: quad-reduce in regs; publish AFTER the barrier (P dead) ----
#pragma unroll
    for (int g = 0; g < 4; ++g) {
        lsum[g] += __shfl_xor(lsum[g], 16);
        lsum[g] += __shfl_xor(lsum[g], 32);
    }
    __syncthreads();   // all P strips consumed; combine bufs + l usable
    if (quad == 0) {
#pragma unroll
        for (int g = 0; g < 4; ++g)
            aF[LOFF + w * 64 + g * 16 + q15] = lsum[g];
    }

    // ---- 8-way tree combine of o through LDS (rows padded to OSTR=68) ----
#define OWRITE(idx)                                                          \
    {                                                                        \
        float* b = aF + (idx) * OBUF;                                        \
        _Pragma("unroll") for (int g = 0; g < 4; ++g)                        \
        _Pragma("unroll") for (int dt = 0; dt < 4; ++dt) {                   \
            b[(g * 16 + quad * 4 + 0) * OSTR + dt * 16 + q15] = oacc[g][dt].x; \
            b[(g * 16 + quad * 4 + 1) * OSTR + dt * 16 + q15] = oacc[g][dt].y; \
            b[(g * 16 + quad * 4 + 2) * OSTR + dt * 16 + q15] = oacc[g][dt].z; \
            b[(g * 16 + quad * 4 + 3) * OSTR + dt * 16 + q15] = oacc[g][dt].w; \
        }                                                                    \
    }
#define OADD(idx)                                                            \
    {                                                                        \
        const float* b = aF + (idx) * OBUF;                                  \
        _Pragma("unroll") for (int g = 0; g < 4; ++g)                        \
        _Pragma("unroll") for (int dt = 0; dt < 4; ++dt) {                   \
            oacc[g][dt].x += b[(g * 16 + quad * 4 + 0) * OSTR + dt * 16 + q15];\
            oacc[g][dt].y += b[(g * 16 + quad * 4 + 1) * OSTR + dt * 16 + q15];\
            oacc[g][dt].z += b[(g * 16 + quad * 4 + 2) * OSTR + dt * 16 + q15];\
            oacc[g][dt].w += b[(g * 16 + quad * 4 + 3) * OSTR + dt * 16 + q15];\
        }                                                                    \
    }
    if (w >= 4) OWRITE(w - 4);
    __syncthreads();
    if (w < 4) OADD(w);
    __syncthreads();
    if (w == 2 || w == 3) OWRITE(w - 2);
    __syncthreads();
    if (w < 2) OADD(w);
    __syncthreads();
    if (w < 2) OWRITE(w);
    __syncthreads();

    {
        const int q  = t >> 3;            // 0..63
        const int d0 = (t & 7) * 8;
        float l = 0.f;
#pragma unroll
        for (int i = 0; i < 8; ++i) l += aF[LOFF + i * 64 + q];
        const float linv = 1.0f / l;
#pragma unroll
        for (int k2 = 0; k2 < 2; ++k2) {
            float4 a = *(const float4*)&aF[q * OSTR + d0 + k2 * 4];
            float4 b = *(const float4*)&aF[OBUF + q * OSTR + d0 + k2 * 4];
            float4 s;
            s.x = (a.x + b.x) * linv; s.y = (a.y + b.y) * linv;
            s.z = (a.z + b.z) * linv; s.w = (a.w + b.w) * linv;
            *(float4*)(out + (base + q0 + q) * 64 + d0 + k2 * 4) = s;
        }
    }
}

// ---------------------------------------------------------------------------
extern "C" void kernel_launch(void* const* d_in, const int* in_sizes, int n_in,
                              void* d_out, int out_size, void* d_ws, size_t ws_size,
                              hipStream_t stream)
{
    const float* ix = (const float*)d_in[0];
    const float* Wk = (const float*)d_in[1];
    const float* Wq = (const float*)d_in[2];
    const float* Wv = (const float*)d_in[3];
    float* out = (float*)d_out;

    // ws: Qw | Kt | Vt (NROW*64 ushorts each) + WTt (24*192*32 ushorts)
    ushort* Qw  = (ushort*)d_ws;
    ushort* Kt  = Qw + (size_t)NROW * Hm;
    ushort* Vt  = Kt + (size_t)NROW * Hm;
    ushort* WTt = Vt + (size_t)NROW * Hm;

    wconv<<<72, 256, 0, stream>>>(Wq, Wk, Wv, WTt);
    proj<<<512, 256, 0, stream>>>(ix, WTt, Qw, Kt, Vt);
    attn<<<256, 512, 0, stream>>>(Qw, Kt, Vt, out);
}

// Round 12
// 127.199 us; speedup vs baseline: 2.0446x; 1.0176x over previous
//
#include <hip/hip_runtime.h>
#include <math.h>

#define Dm   768
#define Hm   64
#define SEQ  4096
#define NB   4
#define NROW (NB * SEQ)

// scale 1/sqrt(64) and log2(e) folded into Wq at wconv time -> exp2 domain
#define QSCALE (0.125f * 1.4426950408889634f)

typedef _Float16 f16;
typedef __attribute__((ext_vector_type(8))) _Float16 f16x8;
typedef __attribute__((ext_vector_type(2))) __fp16 fp16x2_raw;
typedef __attribute__((ext_vector_type(4))) float f32x4;
typedef unsigned int uint;
typedef unsigned short ushort;

#define MFMAH(A, B, C) __builtin_amdgcn_mfma_f32_16x16x32_f16(A, B, C, 0, 0, 0)

__device__ __forceinline__ uint pkrtz(float a, float b) {
    fp16x2_raw r = __builtin_amdgcn_cvt_pkrtz(a, b);
    return __builtin_bit_cast(uint, r);
}
__device__ __forceinline__ ushort f2h(float f) {
    f16 h = (f16)f;
    return __builtin_bit_cast(ushort, h);
}
union F16x8U { uint u[4]; f16x8 v; };

// ---------------------------------------------------------------------------
// R5-EXACT RESUBMISSION (session-best 127.97us). Locks the best measured
// configuration before plateau declaration.
// ---------------------------------------------------------------------------

// ---------------------------------------------------------------------------
// Kernel 0: W -> WTt f16, tiled [kt(24)][c(192)][kk(32)]. Coalesced via
// padded-LDS transpose.
// ---------------------------------------------------------------------------
__global__ __launch_bounds__(256) void wconv(
    const float* __restrict__ Wq, const float* __restrict__ Wk,
    const float* __restrict__ Wv, ushort* __restrict__ WTt)
{
    __shared__ ushort lt[64 * 33];
    const int b  = blockIdx.x;            // 72 = 24 kt x 3 mat
    const int kt = b / 3, m = b - kt * 3;
    const float* W = (m == 0) ? Wq : (m == 1 ? Wk : Wv);
    const float sc = (m == 0) ? QSCALE : 1.0f;
    const int t = threadIdx.x;
#pragma unroll
    for (int p = 0; p < 8; ++p) {
        int t2 = p * 256 + t;
        int kl = t2 >> 6, c = t2 & 63;
        lt[c * 33 + kl] = f2h(W[(size_t)(kt * 32 + kl) * 64 + c] * sc);
    }
    __syncthreads();
#pragma unroll
    for (int p = 0; p < 8; ++p) {
        int t2 = p * 256 + t;
        int c = t2 >> 5, kk = t2 & 31;
        WTt[((size_t)kt * 192 + m * 64 + c) * 32 + kk] = lt[c * 33 + kk];
    }
}

// ---------------------------------------------------------------------------
// Kernel 1: f16 MFMA QKV projection, split-K=4, 32 rows/block (512 blocks).
// B-fragment set reused across two 16-row tiles. LB(256,2), 2 blocks/CU.
// ---------------------------------------------------------------------------
__global__ __launch_bounds__(256, 2) void proj(
    const float* __restrict__ ix, const ushort* __restrict__ WTt,
    ushort* __restrict__ Qw, ushort* __restrict__ Kt, ushort* __restrict__ Vt)
{
    __shared__ __align__(16) float comb[2][2][3072];   // 48 KiB

    const int t    = threadIdx.x;
    const int lane = t & 63;
    const int kh   = __builtin_amdgcn_readfirstlane(t >> 6);  // split-K index
    const int q15  = lane & 15, quad = lane >> 4;
    const int gr0  = blockIdx.x * 32;

    const float* Ab0 = ix + (size_t)(gr0 + q15) * Dm + kh * 192 + quad * 8;
    const float* Ab1 = Ab0 + (size_t)16 * Dm;
    const ushort* Bb = WTt + ((size_t)(kh * 6) * 192 + q15) * 32 + quad * 8;

    f32x4 acc[2][12];
#pragma unroll
    for (int rt = 0; rt < 2; ++rt)
#pragma unroll
        for (int ct = 0; ct < 12; ++ct) acc[rt][ct] = (f32x4){0.f, 0.f, 0.f, 0.f};

    f32x4 Af[2][3][2];   // [tile][ring-3][half], distance-2
#pragma unroll
    for (int i = 0; i < 2; ++i) {
        Af[0][i][0] = *(const f32x4*)(Ab0 + i * 32);
        Af[0][i][1] = *(const f32x4*)(Ab0 + i * 32 + 4);
        Af[1][i][0] = *(const f32x4*)(Ab1 + i * 32);
        Af[1][i][1] = *(const f32x4*)(Ab1 + i * 32 + 4);
    }

#pragma unroll
    for (int it = 0; it < 6; ++it) {
        f16x8 Bf[12];
#pragma unroll
        for (int ct = 0; ct < 12; ++ct)
            Bf[ct] = *(const f16x8*)(Bb + (size_t)it * 6144 + ct * 512);

        if (it + 2 < 6) {
            Af[0][(it + 2) % 3][0] = *(const f32x4*)(Ab0 + (it + 2) * 32);
            Af[0][(it + 2) % 3][1] = *(const f32x4*)(Ab0 + (it + 2) * 32 + 4);
            Af[1][(it + 2) % 3][0] = *(const f32x4*)(Ab1 + (it + 2) * 32);
            Af[1][(it + 2) % 3][1] = *(const f32x4*)(Ab1 + (it + 2) * 32 + 4);
        }

        F16x8U af0, af1;
        af0.u[0] = pkrtz(Af[0][it % 3][0].x, Af[0][it % 3][0].y);
        af0.u[1] = pkrtz(Af[0][it % 3][0].z, Af[0][it % 3][0].w);
        af0.u[2] = pkrtz(Af[0][it % 3][1].x, Af[0][it % 3][1].y);
        af0.u[3] = pkrtz(Af[0][it % 3][1].z, Af[0][it % 3][1].w);
        af1.u[0] = pkrtz(Af[1][it % 3][0].x, Af[1][it % 3][0].y);
        af1.u[1] = pkrtz(Af[1][it % 3][0].z, Af[1][it % 3][0].w);
        af1.u[2] = pkrtz(Af[1][it % 3][1].x, Af[1][it % 3][1].y);
        af1.u[3] = pkrtz(Af[1][it % 3][1].z, Af[1][it % 3][1].w);
        __builtin_amdgcn_s_setprio(1);
#pragma unroll
        for (int ct = 0; ct < 12; ++ct) {
            acc[0][ct] = MFMAH(af0.v, Bf[ct], acc[0][ct]);
            acc[1][ct] = MFMAH(af1.v, Bf[ct], acc[1][ct]);
        }
        __builtin_amdgcn_s_setprio(0);
    }

    if (kh >= 2) {
#pragma unroll
        for (int rt = 0; rt < 2; ++rt)
#pragma unroll
            for (int ct = 0; ct < 12; ++ct)
                *(f32x4*)&comb[rt][kh - 2][(ct * 64 + lane) * 4] = acc[rt][ct];
    }
    __syncthreads();
    if (kh < 2) {
#pragma unroll
        for (int rt = 0; rt < 2; ++rt)
#pragma unroll
            for (int ct = 0; ct < 12; ++ct) {
                f32x4 o = *(const f32x4*)&comb[rt][kh][(ct * 64 + lane) * 4];
                acc[rt][ct].x += o.x; acc[rt][ct].y += o.y;
                acc[rt][ct].z += o.z; acc[rt][ct].w += o.w;
            }
    }
    __syncthreads();
    if (kh == 1) {
#pragma unroll
        for (int rt = 0; rt < 2; ++rt)
#pragma unroll
            for (int ct = 0; ct < 12; ++ct)
                *(f32x4*)&comb[rt][0][(ct * 64 + lane) * 4] = acc[rt][ct];
    }
    __syncthreads();
    if (kh == 0) {
#pragma unroll
        for (int rt = 0; rt < 2; ++rt) {
#pragma unroll
            for (int ct = 0; ct < 12; ++ct) {
                f32x4 o = *(const f32x4*)&comb[rt][0][(ct * 64 + lane) * 4];
                acc[rt][ct].x += o.x; acc[rt][ct].y += o.y;
                acc[rt][ct].z += o.z; acc[rt][ct].w += o.w;
            }
            const int gr  = gr0 + rt * 16;
            const int n4  = gr >> 4;
            const int h16 = n4 & 1;
            const int j32 = gr >> 5;
#pragma unroll
            for (int ct = 0; ct < 12; ++ct) {
                float vals[4] = {acc[rt][ct].x, acc[rt][ct].y, acc[rt][ct].z, acc[rt][ct].w};
                if (ct < 4) {
#pragma unroll
                    for (int r = 0; r < 4; ++r)
                        Qw[(size_t)(gr + quad * 4 + r) * 64 + ct * 16 + q15] = f2h(vals[r]);
                } else if (ct < 8) {
#pragma unroll
                    for (int r = 0; r < 4; ++r)
                        Kt[(size_t)n4 * 1024 + (ct - 4) * 256 + (quad * 4 + r) * 16 + q15] = f2h(vals[r]);
                } else {
                    ushort4 vv;
                    vv.x = f2h(vals[0]); vv.y = f2h(vals[1]);
                    vv.z = f2h(vals[2]); vv.w = f2h(vals[3]);
                    *(ushort4*)(Vt + (size_t)j32 * 2048 + (ct - 8) * 512 +
                                (h16 * 2 + (quad >> 1)) * 128 + q15 * 8 + (quad & 1) * 4) = vv;
                }
            }
        }
    }
}

// ---------------------------------------------------------------------------
// Kernel 2: f16 MFMA flash attention (R5 measured-best). grid 256 x 512.
// Block = 64 queries; wave w owns j in [w*512, +512) = 16 iters of 32 keys.
// Clustered-MFMA pipeline: PFLOAD; setprio(1); QKMM(i+1)->zz regs; PVMM(i);
// setprio(0); LOADKV(i+2, ring-2); SMPACK(i+1). PSTR 40 shorts, 84KB LDS,
// l published before the barrier. 8-way tree combine, rows padded to 68.
// ---------------------------------------------------------------------------
#define OSTR 68
#define OBUF 4352   // 64 rows * 68 floats per combine buffer

__global__ __launch_bounds__(512, 2) void attn(
    const ushort* __restrict__ Qw, const ushort* __restrict__ Kt,
    const ushort* __restrict__ Vt, float* __restrict__ out)
{
    // floats [0,17408): combine bufs (4 x 4352), aliased by P strips during
    // the loop (shorts [0, 8*5120)). floats [20480,20992): l per wave.
    __shared__ __align__(16) float aF[20992];   // 83968 B
    short* aS = (short*)aF;

    const int t    = threadIdx.x;
    const int lane = t & 63;
    const int w    = __builtin_amdgcn_readfirstlane(t >> 6);
    const int q15  = lane & 15, quad = lane >> 4;

    const int bb    = blockIdx.x;
    const int xcd   = bb & 7;
    const int batch = xcd >> 1;
    const int slot  = (bb >> 3) | ((xcd & 1) << 5);   // 0..63
    const int q0    = slot * 64;
    const size_t base = (size_t)batch * SEQ;

    f16x8 qf[4][2];
#pragma unroll
    for (int g = 0; g < 4; ++g)
#pragma unroll
        for (int h = 0; h < 2; ++h)
            qf[g][h] = *(const f16x8*)(Qw + (base + q0 + g * 16 + q15) * 64 + h * 32 + quad * 8);

    f32x4 oacc[4][4];
#pragma unroll
    for (int g = 0; g < 4; ++g)
#pragma unroll
        for (int dt = 0; dt < 4; ++dt) oacc[g][dt] = (f32x4){0.f, 0.f, 0.f, 0.f};
    float lsum[4] = {0.f, 0.f, 0.f, 0.f};

    const size_t j0g = base + w * 512;
    const ushort* Kfb = Kt + (j0g >> 4) * 1024;
    const ushort* Vfb = Vt + (j0g >> 5) * 2048 + lane * 8;
    short* Ps = aS + w * 5120;                          // 2 bufs x [64 q][40]

    int koff[2][2];
#pragma unroll
    for (int jt = 0; jt < 2; ++jt)
#pragma unroll
        for (int h = 0; h < 2; ++h)
            koff[jt][h] = jt * 1024 + h * 512 + (quad >> 1) * 256 + q15 * 16 + (quad & 1) * 8;

    f16x8 kf[2][2][2], vf[2][4];   // ring-2
    f32x4 zz[4][2];                // deferred QK results (tile i+1)
    f16x8 pf[4];

#define LOADKV(slotc, i)                                                       \
    {                                                                          \
        _Pragma("unroll") for (int jt = 0; jt < 2; ++jt)                       \
        _Pragma("unroll") for (int h = 0; h < 2; ++h)                          \
            kf[slotc][jt][h] = *(const f16x8*)(Kfb + (size_t)(i) * 2048 + koff[jt][h]); \
        _Pragma("unroll") for (int dt = 0; dt < 4; ++dt)                       \
            vf[slotc][dt] = *(const f16x8*)(Vfb + (size_t)(i) * 2048 + dt * 512); \
    }
#define QKMM(slotc)                                                            \
    {                                                                          \
        _Pragma("unroll") for (int g = 0; g < 4; ++g)                          \
        _Pragma("unroll") for (int jt = 0; jt < 2; ++jt) {                     \
            f32x4 z = (f32x4){0.f, 0.f, 0.f, 0.f};                             \
            z = MFMAH(kf[slotc][jt][0], qf[g][0], z);                          \
            z = MFMAH(kf[slotc][jt][1], qf[g][1], z);                          \
            zz[g][jt] = z;                                                     \
        }                                                                      \
    }
#define SMPACK(pb)                                                             \
    {                                                                          \
        _Pragma("unroll") for (int g = 0; g < 4; ++g)                          \
        _Pragma("unroll") for (int jt = 0; jt < 2; ++jt) {                     \
            float e0 = exp2f(zz[g][jt].x), e1 = exp2f(zz[g][jt].y);            \
            float e2 = exp2f(zz[g][jt].z), e3 = exp2f(zz[g][jt].w);            \
            lsum[g] += (e0 + e1) + (e2 + e3);                                  \
            uint2 pk = make_uint2(pkrtz(e0, e1), pkrtz(e2, e3));               \
            *(uint2*)(Ps + (pb) * 2560 + (g * 16 + q15) * 40 + jt * 16 + quad * 4) = pk; \
        }                                                                      \
    }
#define PFLOAD(pb)                                                             \
    {                                                                          \
        _Pragma("unroll") for (int g = 0; g < 4; ++g)                          \
            pf[g] = *(const f16x8*)(Ps + (pb) * 2560 + (g * 16 + q15) * 40 + quad * 8); \
    }
#define PVMM(slotc)                                                            \
    {                                                                          \
        _Pragma("unroll") for (int dt = 0; dt < 4; ++dt)                       \
        _Pragma("unroll") for (int g = 0; g < 4; ++g)                          \
            oacc[g][dt] = MFMAH(pf[g], vf[slotc][dt], oacc[g][dt]);            \
    }

    LOADKV(0, 0);
    LOADKV(1, 1);
    QKMM(0);
    SMPACK(0);
#pragma unroll
    for (int i = 0; i < 16; ++i) {
        PFLOAD(i & 1);                       // early ds_read, used in PVMM
        __builtin_amdgcn_s_setprio(1);
        if (i + 1 < 16) QKMM((i + 1) & 1);   // 16 MFMA -> zz (kept in regs)
        PVMM(i & 1);                         // 16 MFMA, tile i
        __builtin_amdgcn_s_setprio(0);
        if (i + 2 < 16) LOADKV(i & 1, i + 2);// ring-2 slot just freed
        if (i + 1 < 16) SMPACK((i + 1) & 1); // softmax in next-body MFMA shadow
    }

    // ---- l: quad-reduce, publish per wave ----
#pragma unroll
    for (int g = 0; g < 4; ++g) {
        lsum[g] += __shfl_xor(lsum[g], 16);
        lsum[g] += __shfl_xor(lsum[g], 32);
    }
    if (quad == 0) {
#pragma unroll
        for (int g = 0; g < 4; ++g)
            aF[20480 + w * 64 + g * 16 + q15] = lsum[g];
    }
    __syncthreads();   // P strips dead; l published; combine bufs usable

    // ---- 8-way tree combine of o through LDS (rows padded to OSTR=68) ----
#define OWRITE(idx)                                                          \
    {                                                                        \
        float* b = aF + (idx) * OBUF;                                        \
        _Pragma("unroll") for (int g = 0; g < 4; ++g)                        \
        _Pragma("unroll") for (int dt = 0; dt < 4; ++dt) {                   \
            b[(g * 16 + quad * 4 + 0) * OSTR + dt * 16 + q15] = oacc[g][dt].x; \
            b[(g * 16 + quad * 4 + 1) * OSTR + dt * 16 + q15] = oacc[g][dt].y; \
            b[(g * 16 + quad * 4 + 2) * OSTR + dt * 16 + q15] = oacc[g][dt].z; \
            b[(g * 16 + quad * 4 + 3) * OSTR + dt * 16 + q15] = oacc[g][dt].w; \
        }                                                                    \
    }
#define OADD(idx)                                                            \
    {                                                                        \
        const float* b = aF + (idx) * OBUF;                                  \
        _Pragma("unroll") for (int g = 0; g < 4; ++g)                        \
        _Pragma("unroll") for (int dt = 0; dt < 4; ++dt) {                   \
            oacc[g][dt].x += b[(g * 16 + quad * 4 + 0) * OSTR + dt * 16 + q15];\
            oacc[g][dt].y += b[(g * 16 + quad * 4 + 1) * OSTR + dt * 16 + q15];\
            oacc[g][dt].z += b[(g * 16 + quad * 4 + 2) * OSTR + dt * 16 + q15];\
            oacc[g][dt].w += b[(g * 16 + quad * 4 + 3) * OSTR + dt * 16 + q15];\
        }                                                                    \
    }
    if (w >= 4) OWRITE(w - 4);
    __syncthreads();
    if (w < 4) OADD(w);
    __syncthreads();
    if (w == 2 || w == 3) OWRITE(w - 2);
    __syncthreads();
    if (w < 2) OADD(w);
    __syncthreads();
    if (w < 2) OWRITE(w);
    __syncthreads();

    {
        const int q  = t >> 3;            // 0..63
        const int d0 = (t & 7) * 8;
        float l = 0.f;
#pragma unroll
        for (int i = 0; i < 8; ++i) l += aF[20480 + i * 64 + q];
        const float linv = 1.0f / l;
#pragma unroll
        for (int k2 = 0; k2 < 2; ++k2) {
            float4 a = *(const float4*)&aF[q * OSTR + d0 + k2 * 4];
            float4 b = *(const float4*)&aF[OBUF + q * OSTR + d0 + k2 * 4];
            float4 s;
            s.x = (a.x + b.x) * linv; s.y = (a.y + b.y) * linv;
            s.z = (a.z + b.z) * linv; s.w = (a.w + b.w) * linv;
            *(float4*)(out + (base + q0 + q) * 64 + d0 + k2 * 4) = s;
        }
    }
}

// ---------------------------------------------------------------------------
extern "C" void kernel_launch(void* const* d_in, const int* in_sizes, int n_in,
                              void* d_out, int out_size, void* d_ws, size_t ws_size,
                              hipStream_t stream)
{
    const float* ix = (const float*)d_in[0];
    const float* Wk = (const float*)d_in[1];
    const float* Wq = (const float*)d_in[2];
    const float* Wv = (const float*)d_in[3];
    float* out = (float*)d_out;

    // ws: Qw | Kt | Vt (NROW*64 ushorts each) + WTt (24*192*32 ushorts)
    ushort* Qw  = (ushort*)d_ws;
    ushort* Kt  = Qw + (size_t)NROW * Hm;
    ushort* Vt  = Kt + (size_t)NROW * Hm;
    ushort* WTt = Vt + (size_t)NROW * Hm;

    wconv<<<72, 256, 0, stream>>>(Wq, Wk, Wv, WTt);
    proj<<<512, 256, 0, stream>>>(ix, WTt, Qw, Kt, Vt);
    attn<<<256, 512, 0, stream>>>(Qw, Kt, Vt, out);
}